// Round 6
// baseline (16863.023 us; speedup 1.0000x reference)
//
#include <hip/hip_runtime.h>
#include <math.h>

#define T_SEQ 2048
#define S_SEQ 2050   // T + 2
#define NTAG 12
#define START_TAG 10
#define STOP_TAG 11
#define NBLK 32      // blocks per LSTM stream

typedef float f32x8 __attribute__((ext_vector_type(8)));

// ---------------------------------------------------------------------------
// Generic fp32 GEMM: C[M,N] = Aacc[M,K] @ W[N,K]^T + bias, fused epilogues.
// amode 0: A[r][k] direct (row r possibly reversed). amode 1: concat of two
// h-buffers: lo[r] = concat(Hf[r], Hb[S-1-r]).
// epi 0: +bias; 1: elu(+bias)+Aacc(m,n) residual; 2: elu(+bias); 3: (+bias)*MUL
// When launched with gridDim.z > 1, per-z pointer arrays override W/bias/C/
// Hf/Hb/rev (batches the 4 independent (lstm,dir) streams in one dispatch).
// ---------------------------------------------------------------------------
struct GemmP {
  const float* W; const float* bias; float* C;
  int M, N, K;
  int amode; const float* A; int lda; int rev; int rowoff;
  const float* Hf; const float* Hb;
  int epi; const float* MUL;
  const float* Wz[4]; const float* biasz[4]; float* Cz[4];
  const float* Hfz[4]; const float* Hbz[4]; int revz[4];
};

__device__ __forceinline__ float aacc(const GemmP& p, int m, int k) {
  int r = p.rowoff + m;
  if (p.rev) r = (S_SEQ - 1) - r;
  if (p.amode == 0) return p.A[(size_t)r * p.lda + k];
  return (k < 512) ? p.Hf[(size_t)r * 512 + k]
                   : p.Hb[(size_t)(S_SEQ - 1 - r) * 512 + (k - 512)];
}

__global__ __launch_bounds__(256) void gemm_k(GemmP p) {
  if (gridDim.z > 1) {
    const int z = blockIdx.z;
    p.W = p.Wz[z]; p.bias = p.biasz[z]; p.C = p.Cz[z];
    p.Hf = p.Hfz[z]; p.Hb = p.Hbz[z]; p.rev = p.revz[z];
  }
  __shared__ float As[16][136];
  __shared__ float Bs[16][136];
  const int t  = threadIdx.x;
  const int tx = t & 15, ty = t >> 4;
  const int m0 = blockIdx.y * 128, n0 = blockIdx.x * 128;

  float acc[8][8];
#pragma unroll
  for (int i = 0; i < 8; ++i)
#pragma unroll
    for (int j = 0; j < 8; ++j) acc[i][j] = 0.f;

  const int KT  = (p.K + 15) >> 4;
  const int kk  = t & 15;
  const int sub = t >> 4;

  for (int kt = 0; kt < KT; ++kt) {
    const int k   = (kt << 4) + kk;
    const bool kok = (k < p.K);
#pragma unroll
    for (int l = 0; l < 8; ++l) {
      int mm = sub * 8 + l;
      int m = m0 + mm;
      As[kk][mm] = (kok && m < p.M) ? aacc(p, m, k) : 0.f;
      int n = n0 + mm;
      Bs[kk][mm] = (kok && n < p.N) ? p.W[(size_t)n * p.K + k] : 0.f;
    }
    __syncthreads();
#pragma unroll
    for (int q = 0; q < 16; ++q) {
      const float4 a0 = *(const float4*)&As[q][ty * 4];
      const float4 a1 = *(const float4*)&As[q][64 + ty * 4];
      const float4 b0 = *(const float4*)&Bs[q][tx * 4];
      const float4 b1 = *(const float4*)&Bs[q][64 + tx * 4];
      const float av[8] = {a0.x, a0.y, a0.z, a0.w, a1.x, a1.y, a1.z, a1.w};
      const float bv[8] = {b0.x, b0.y, b0.z, b0.w, b1.x, b1.y, b1.z, b1.w};
#pragma unroll
      for (int i = 0; i < 8; ++i)
#pragma unroll
        for (int j = 0; j < 8; ++j) acc[i][j] += av[i] * bv[j];
    }
    __syncthreads();
  }

#pragma unroll
  for (int i = 0; i < 8; ++i) {
    int m = m0 + (i < 4 ? ty * 4 + i : 64 + ty * 4 + (i - 4));
    if (m >= p.M) continue;
#pragma unroll
    for (int j = 0; j < 8; ++j) {
      int n = n0 + (j < 4 ? tx * 4 + j : 64 + tx * 4 + (j - 4));
      if (n >= p.N) continue;
      float v = acc[i][j] + p.bias[n];
      if (p.epi == 1)      v = (v > 0.f ? v : expm1f(v)) + aacc(p, m, n);
      else if (p.epi == 2) v = (v > 0.f ? v : expm1f(v));
      else if (p.epi == 3) v = v * p.MUL[(size_t)m * p.N + n];
      p.C[(size_t)m * p.N + n] = v;
    }
  }
}

// ---------------------------------------------------------------------------
// Persistent recurrent LSTM layer: 4 streams (lstm x dir), NBLK blocks each,
// 512 threads/block. Block b owns h indices [16b,16b+16) -> 64 gate rows;
// wave og (0..7) owns gate rows og*8..og*8+7; lane p (0..63) holds 8 weights
// per row at stride 64 (named f32x8 vars -> guaranteed VGPR residency,
// ~64 weight regs + ~40 overhead, under the 128-reg/4-wave budget).
// Cross-block traffic exclusively via relaxed agent-scope atomics (IF$-
// coherent, no wbl2/inv fences); h-stores ordered before the counter add by
// program order within wave 0 after an explicit s_waitcnt vmcnt(0).
// ---------------------------------------------------------------------------
__global__ __launch_bounds__(512, 2) void lstm_layer_k(
    const float* __restrict__ Whh_u, const float* __restrict__ Whh_p,
    const float* __restrict__ XP,    // [4][S_SEQ][2048]
    float* __restrict__ Hout,        // [4][S_SEQ][512]
    int* __restrict__ cnt,           // [4][S_SEQ]
    int layer) {
  const int bid = blockIdx.x;
  const int s = bid & 3;        // stream: (lstm<<1)|dir
  const int b = bid >> 2;       // 0..NBLK-1
  const int t = threadIdx.x;    // 0..511
  const int p = t & 63;         // lane
  const int og = t >> 6;        // wave 0..7

  const float* W2 = ((s >> 1) ? Whh_p : Whh_u) +
                    (size_t)(layer * 2 + (s & 1)) * 2048 * 512;
  const float* xp = XP + (size_t)s * S_SEQ * 2048;
  float* hout = Hout + (size_t)s * S_SEQ * 512;
  int* c_ = cnt + s * S_SEQ;

  __shared__ float h_lds[512];
  __shared__ float xp_lds[64];
  __shared__ float gates[64];

  // Register-resident weights: 8 named f32x8, statically indexed everywhere.
  f32x8 w0, w1, w2, w3, w4, w5, w6, w7;
#define LOADW(i)                                                         \
  {                                                                      \
    const int fr = og * 8 + i;                                           \
    const int row = ((fr >> 4) << 9) + (b << 4) + (fr & 15);             \
    const float* wr = W2 + (size_t)row * 512 + p;                        \
    w##i = (f32x8){wr[0],   wr[64],  wr[128], wr[192],                   \
                   wr[256], wr[320], wr[384], wr[448]};                  \
  }
  LOADW(0) LOADW(1) LOADW(2) LOADW(3) LOADW(4) LOADW(5) LOADW(6) LOADW(7)
#undef LOADW

  const int row64 = ((t >> 4) << 9) + (b << 4) + (t & 15);  // for t<64
  float xr = (t < 64) ? xp[row64] : 0.f;

  for (int i = t; i < 512; i += 512) h_lds[i] = 0.f;
  float creg = 0.f;
  __syncthreads();

  for (int step = 0; step < S_SEQ; ++step) {
    if (t < 64) xp_lds[t] = xr;   // xp for current step
    __syncthreads();              // xp_lds + h_lds ready

    // prefetch next step's xp into register (hidden under the dot product)
    if (t < 64 && step + 1 < S_SEQ)
      xr = xp[(size_t)(step + 1) * 2048 + row64];

    float a0 = 0.f, a1 = 0.f, a2 = 0.f, a3 = 0.f;
    float a4 = 0.f, a5 = 0.f, a6 = 0.f, a7 = 0.f;
#pragma unroll
    for (int e = 0; e < 8; ++e) {
      const float hv = h_lds[p + (e << 6)];
      a0 += w0[e] * hv; a1 += w1[e] * hv; a2 += w2[e] * hv; a3 += w3[e] * hv;
      a4 += w4[e] * hv; a5 += w5[e] * hv; a6 += w6[e] * hv; a7 += w7[e] * hv;
    }
#pragma unroll
    for (int d = 32; d >= 1; d >>= 1) {
      a0 += __shfl_xor(a0, d, 64); a1 += __shfl_xor(a1, d, 64);
      a2 += __shfl_xor(a2, d, 64); a3 += __shfl_xor(a3, d, 64);
      a4 += __shfl_xor(a4, d, 64); a5 += __shfl_xor(a5, d, 64);
      a6 += __shfl_xor(a6, d, 64); a7 += __shfl_xor(a7, d, 64);
    }
    if (p == 0) {
      const int fb = og * 8;
      gates[fb + 0] = a0 + xp_lds[fb + 0];
      gates[fb + 1] = a1 + xp_lds[fb + 1];
      gates[fb + 2] = a2 + xp_lds[fb + 2];
      gates[fb + 3] = a3 + xp_lds[fb + 3];
      gates[fb + 4] = a4 + xp_lds[fb + 4];
      gates[fb + 5] = a5 + xp_lds[fb + 5];
      gates[fb + 6] = a6 + xp_lds[fb + 6];
      gates[fb + 7] = a7 + xp_lds[fb + 7];
    }
    __syncthreads();

    if (t < 16) {
      const float gi = gates[t], gf = gates[16 + t];
      const float gg = gates[32 + t], go = gates[48 + t];
      const float si = 1.f / (1.f + __expf(-gi));
      const float sf = 1.f / (1.f + __expf(-gf));
      const float so = 1.f / (1.f + __expf(-go));
      creg = sf * creg + si * tanhf(gg);
      const float h = so * tanhf(creg);
      __hip_atomic_store(&hout[(size_t)step * 512 + (b << 4) + t], h,
                         __ATOMIC_RELAXED, __HIP_MEMORY_SCOPE_AGENT);
    }
    // Drain write-through stores to the coherence point. Storing lanes
    // (t<16) and the signaling lane (t==0) are in the same wave ->
    // program order suffices after this wait.
    asm volatile("s_waitcnt vmcnt(0)" ::: "memory");
    if (t == 0) {
      __hip_atomic_fetch_add(&c_[step], 1, __ATOMIC_RELAXED,
                             __HIP_MEMORY_SCOPE_AGENT);
      while (__hip_atomic_load(&c_[step], __ATOMIC_RELAXED,
                               __HIP_MEMORY_SCOPE_AGENT) < NBLK) {
      }
    }
    __syncthreads();
    h_lds[t] = __hip_atomic_load(&hout[(size_t)step * 512 + t],
                                 __ATOMIC_RELAXED, __HIP_MEMORY_SCOPE_AGENT);
    // loop-top __syncthreads() orders these h_lds writes before next reads
  }
}

// ---------------------------------------------------------------------------
// CRF: sequential scans (wave0 unary, wave1 pairwise) + score gathers
// (waves 2/3), then combine. Single block; in-wave lockstep avoids barriers.
// ---------------------------------------------------------------------------
__global__ __launch_bounds__(256) void crf_k(const float* __restrict__ FU,
                                             const float* __restrict__ FPp,
                                             const float* __restrict__ trans,
                                             const int* __restrict__ tags,
                                             float* __restrict__ out) {
  __shared__ float tr[144];
  __shared__ float fvU[NTAG];
  __shared__ float fvP[NTAG];
  __shared__ float pf[160];
  __shared__ float sc[2];
  const int t = threadIdx.x;
  if (t < 144) tr[t] = trans[t];
  if (t < NTAG) {
    fvU[t] = (t == START_TAG) ? 0.f : -100.f;
    fvP[t] = 0.f;
  }
  __syncthreads();
  const int w = t >> 6, l = t & 63;

  if (w == 0) {  // unary forward scan
    float featc = (l < NTAG) ? FU[l] : 0.f;
    for (int step = 0; step < T_SEQ; ++step) {
      float featn = 0.f;
      if (l < NTAG && step + 1 < T_SEQ) featn = FU[(size_t)(step + 1) * NTAG + l];
      if (l < NTAG) {
        float m = -1e30f;
#pragma unroll
        for (int i = 0; i < NTAG; ++i) m = fmaxf(m, fvU[i] + tr[i * NTAG + l]);
        float ss = 0.f;
#pragma unroll
        for (int i = 0; i < NTAG; ++i)
          ss += __expf(fvU[i] + tr[i * NTAG + l] - m);
        fvU[l] = m + __logf(ss) + featc;
      }
      featc = featn;
    }
  } else if (w == 1) {  // pairwise forward scan
    for (int q = l; q < 144; q += 64) pf[q] = FPp[q];
    for (int step = 0; step < T_SEQ + 1; ++step) {
      float nx0 = 0.f, nx1 = 0.f, nx2 = 0.f;
      if (step + 1 < T_SEQ + 1) {
        const float* src = FPp + (size_t)(step + 1) * 144;
        nx0 = src[l];
        nx1 = src[l + 64];
        if (l < 16) nx2 = src[l + 128];
      }
      float nf = 0.f;
      if (l < NTAG) {
        float m = -1e30f;
#pragma unroll
        for (int i = 0; i < NTAG; ++i) m = fmaxf(m, fvP[i] + pf[i * NTAG + l]);
        float ss = 0.f;
#pragma unroll
        for (int i = 0; i < NTAG; ++i)
          ss += __expf(fvP[i] + pf[i * NTAG + l] - m);
        nf = m + __logf(ss);
      }
      pf[l] = nx0;
      pf[l + 64] = nx1;
      if (l < 16) pf[l + 128] = nx2;
      if (l < NTAG) fvP[l] = nf;
    }
  } else if (w == 2) {  // score_u
    float acc = 0.f;
    for (int i = l; i < T_SEQ; i += 64) {
      const int tg = tags[i];
      const int pv = (i == 0) ? START_TAG : tags[i - 1];
      acc += FU[(size_t)i * NTAG + tg] + tr[pv * NTAG + tg];
    }
    if (l == 0) acc += tr[tags[T_SEQ - 1] * NTAG + STOP_TAG];
#pragma unroll
    for (int d = 32; d >= 1; d >>= 1) acc += __shfl_xor(acc, d, 64);
    if (l == 0) sc[0] = acc;
  } else {  // score_p
    float acc = 0.f;
    for (int i = l; i < T_SEQ + 1; i += 64) {
      const int a = (i == 0) ? START_TAG : tags[i - 1];
      const int b2 = (i < T_SEQ) ? tags[i] : STOP_TAG;
      acc += FPp[(size_t)i * 144 + a * NTAG + b2];
    }
#pragma unroll
    for (int d = 32; d >= 1; d >>= 1) acc += __shfl_xor(acc, d, 64);
    if (l == 0) sc[1] = acc;
  }
  __syncthreads();
  if (t == 0) {
    float m = -1e30f;
    for (int i = 0; i < NTAG; ++i)
      m = fmaxf(m, fvU[i] + tr[i * NTAG + STOP_TAG]);
    float ss = 0.f;
    for (int i = 0; i < NTAG; ++i)
      ss += __expf(fvU[i] + tr[i * NTAG + STOP_TAG] - m);
    const float alpha_u = m + __logf(ss);
    float m2 = -1e30f;
    for (int i = 0; i < NTAG; ++i) m2 = fmaxf(m2, fvP[i]);
    float s2 = 0.f;
    for (int i = 0; i < NTAG; ++i) s2 += __expf(fvP[i] - m2);
    const float alpha_p = m2 + __logf(s2);
    out[0] = alpha_u - sc[0] + alpha_p - sc[1];
  }
}

// ---------------------------------------------------------------------------
// Workspace layout (float offsets)
// ---------------------------------------------------------------------------
static const size_t F_XP  = 0;                         // 4*2050*2048
static const size_t F_H0  = 16793600;                  // 4*2050*512
static const size_t F_H1  = 20992000;                  // 4*2050*512
static const size_t F_FC  = 25190400;                  // 2048*1024
static const size_t F_FU  = 27287552;                  // 2048*12
static const size_t F_UB  = 27312128;                  // 2049*512
static const size_t F_HP  = 28361216;                  // 2049*512
static const size_t F_FI  = 29410304;                  // 2049*300
static const size_t F_FO  = 30025004;                  // 2049*300
static const size_t F_FP  = 30639704;                  // 2049*144
static const size_t F_CNT = 30934760;                  // 2*4*2050 ints

extern "C" void kernel_launch(void* const* d_in, const int* in_sizes, int n_in,
                              void* d_out, int out_size, void* d_ws,
                              size_t ws_size, hipStream_t stream) {
  (void)in_sizes; (void)n_in; (void)out_size; (void)ws_size;
  const float* embeds = (const float*)d_in[0];
  const int*   tags   = (const int*)d_in[1];
  const float* uWih   = (const float*)d_in[2];
  const float* uWhh   = (const float*)d_in[3];
  const float* ub     = (const float*)d_in[4];
  const float* pWih   = (const float*)d_in[5];
  const float* pWhh   = (const float*)d_in[6];
  const float* pb     = (const float*)d_in[7];
  const float* ufcW   = (const float*)d_in[8];
  const float* ufcb   = (const float*)d_in[9];
  const float* h2tW   = (const float*)d_in[10];
  const float* h2tb   = (const float*)d_in[11];
  const float* trans  = (const float*)d_in[12];
  const float* UW     = (const float*)d_in[13];
  const float* Ub     = (const float*)d_in[14];
  const float* VW     = (const float*)d_in[15];
  const float* Vb     = (const float*)d_in[16];
  const float* PW     = (const float*)d_in[17];
  const float* Pb     = (const float*)d_in[18];
  const float* pwW    = (const float*)d_in[19];
  const float* pwb    = (const float*)d_in[20];
  const float* ppW    = (const float*)d_in[21];
  const float* ppb    = (const float*)d_in[22];
  float* out = (float*)d_out;
  float* F = (float*)d_ws;
  int* CNT = (int*)(F + F_CNT);

  (void)hipMemsetAsync(CNT, 0, (size_t)2 * 4 * S_SEQ * sizeof(int), stream);

  auto launch = [&](const GemmP& p) {
    dim3 g((p.N + 127) / 128, (p.M + 127) / 128);
    gemm_k<<<g, 256, 0, stream>>>(p);
  };
  auto launch4 = [&](const GemmP& p) {
    dim3 g((p.N + 127) / 128, (p.M + 127) / 128, 4);
    gemm_k<<<g, 256, 0, stream>>>(p);
  };

  // ---- layer-0 xp (4 streams, one dispatch) ----
  {
    GemmP p{};
    p.M = S_SEQ; p.N = 2048; p.K = 1024;
    p.amode = 0; p.A = embeds; p.lda = 1024; p.rowoff = 0;
    p.epi = 0;
    for (int s = 0; s < 4; ++s) {
      const int lstm = s >> 1, d = s & 1;
      p.Wz[s]    = (lstm ? pWih : uWih) + (size_t)d * 2048 * 1024;
      p.biasz[s] = (lstm ? pb : ub) + (size_t)d * 2048;
      p.Cz[s]    = F + F_XP + (size_t)s * S_SEQ * 2048;
      p.revz[s]  = d;
      p.Hfz[s] = nullptr; p.Hbz[s] = nullptr;
    }
    p.W = p.Wz[0]; p.bias = p.biasz[0]; p.C = p.Cz[0]; p.rev = 0;
    launch4(p);
  }
  lstm_layer_k<<<4 * NBLK, 512, 0, stream>>>(uWhh, pWhh, F + F_XP, F + F_H0,
                                             CNT, 0);
  // ---- layer-1 xp (4 streams, one dispatch) ----
  {
    GemmP p{};
    p.M = S_SEQ; p.N = 2048; p.K = 1024;
    p.amode = 1; p.rowoff = 0;
    p.epi = 0;
    for (int s = 0; s < 4; ++s) {
      const int lstm = s >> 1, d = s & 1;
      p.Wz[s]    = (lstm ? pWih : uWih) + (size_t)(2 + d) * 2048 * 1024;
      p.biasz[s] = (lstm ? pb : ub) + (size_t)(2 + d) * 2048;
      p.Cz[s]    = F + F_XP + (size_t)s * S_SEQ * 2048;
      p.revz[s]  = d;
      p.Hfz[s]   = F + F_H0 + (size_t)(lstm * 2 + 0) * S_SEQ * 512;
      p.Hbz[s]   = F + F_H0 + (size_t)(lstm * 2 + 1) * S_SEQ * 512;
    }
    p.W = p.Wz[0]; p.bias = p.biasz[0]; p.C = p.Cz[0]; p.rev = 0;
    p.Hf = p.Hfz[0]; p.Hb = p.Hbz[0];
    launch4(p);
  }
  lstm_layer_k<<<4 * NBLK, 512, 0, stream>>>(uWhh, pWhh, F + F_XP, F + F_H1,
                                             CNT + 4 * S_SEQ, 1);
  // ---- unary head ----
  {
    GemmP p{};
    p.W = ufcW; p.bias = ufcb; p.C = F + F_FC;
    p.M = 2048; p.N = 1024; p.K = 1024;
    p.amode = 1; p.rev = 0; p.rowoff = 1;
    p.Hf = F + F_H1; p.Hb = F + F_H1 + (size_t)1 * S_SEQ * 512;
    p.epi = 1;
    launch(p);
  }
  {
    GemmP p{};
    p.W = h2tW; p.bias = h2tb; p.C = F + F_FU;
    p.M = 2048; p.N = 12; p.K = 1024;
    p.amode = 0; p.A = F + F_FC; p.lda = 1024; p.rev = 0; p.rowoff = 0;
    p.epi = 0;
    launch(p);
  }
  // ---- pairwise head ----
  {
    GemmP p{};
    p.W = UW; p.bias = Ub; p.C = F + F_UB;
    p.M = 2049; p.N = 512; p.K = 1024;
    p.amode = 1; p.rev = 0; p.rowoff = 0;
    p.Hf = F + F_H1 + (size_t)2 * S_SEQ * 512;
    p.Hb = F + F_H1 + (size_t)3 * S_SEQ * 512;
    p.epi = 0;
    launch(p);
  }
  {
    GemmP p{};
    p.W = VW; p.bias = Vb; p.C = F + F_HP;
    p.M = 2049; p.N = 512; p.K = 1024;
    p.amode = 1; p.rev = 0; p.rowoff = 1;
    p.Hf = F + F_H1 + (size_t)2 * S_SEQ * 512;
    p.Hb = F + F_H1 + (size_t)3 * S_SEQ * 512;
    p.epi = 3; p.MUL = F + F_UB;
    launch(p);
  }
  {
    GemmP p{};
    p.W = PW; p.bias = Pb; p.C = F + F_FI;
    p.M = 2049; p.N = 300; p.K = 512;
    p.amode = 0; p.A = F + F_HP; p.lda = 512; p.rev = 0; p.rowoff = 0;
    p.epi = 2;
    launch(p);
  }
  {
    GemmP p{};
    p.W = pwW; p.bias = pwb; p.C = F + F_FO;
    p.M = 2049; p.N = 300; p.K = 300;
    p.amode = 0; p.A = F + F_FI; p.lda = 300; p.rev = 0; p.rowoff = 0;
    p.epi = 1;
    launch(p);
  }
  {
    GemmP p{};
    p.W = ppW; p.bias = ppb; p.C = F + F_FP;
    p.M = 2049; p.N = 144; p.K = 300;
    p.amode = 0; p.A = F + F_FO; p.lda = 300; p.rev = 0; p.rowoff = 0;
    p.epi = 0;
    launch(p);
  }
  crf_k<<<1, 256, 0, stream>>>(F + F_FU, F + F_FP, trans, tags, out);
}

// Round 8
// 15791.231 us; speedup vs baseline: 1.0679x; 1.0679x over previous
//
#include <hip/hip_runtime.h>
#include <math.h>

#define T_SEQ 2048
#define S_SEQ 2050   // T + 2
#define NTAG 12
#define START_TAG 10
#define STOP_TAG 11
#define NBLK 32      // blocks per LSTM stream
#define SENT_U 0xFFFFFFFFu   // memset(0xFF) sentinel: NaN bit pattern, h in (-1,1) never produces it

typedef float f32x8 __attribute__((ext_vector_type(8)));

// ---------------------------------------------------------------------------
// Generic fp32 GEMM: C[M,N] = Aacc[M,K] @ W[N,K]^T + bias, fused epilogues.
// amode 0: A[r][k] direct (row r possibly reversed). amode 1: concat of two
// h-buffers: lo[r] = concat(Hf[r], Hb[S-1-r]).
// epi 0: +bias; 1: elu(+bias)+Aacc(m,n) residual; 2: elu(+bias); 3: (+bias)*MUL
// gridDim.z > 1: per-z pointer arrays override W/bias/C/Hf/Hb/rev.
// ---------------------------------------------------------------------------
struct GemmP {
  const float* W; const float* bias; float* C;
  int M, N, K;
  int amode; const float* A; int lda; int rev; int rowoff;
  const float* Hf; const float* Hb;
  int epi; const float* MUL;
  const float* Wz[4]; const float* biasz[4]; float* Cz[4];
  const float* Hfz[4]; const float* Hbz[4]; int revz[4];
};

__device__ __forceinline__ float aacc(const GemmP& p, int m, int k) {
  int r = p.rowoff + m;
  if (p.rev) r = (S_SEQ - 1) - r;
  if (p.amode == 0) return p.A[(size_t)r * p.lda + k];
  return (k < 512) ? p.Hf[(size_t)r * 512 + k]
                   : p.Hb[(size_t)(S_SEQ - 1 - r) * 512 + (k - 512)];
}

__global__ __launch_bounds__(256) void gemm_k(GemmP p) {
  if (gridDim.z > 1) {
    const int z = blockIdx.z;
    p.W = p.Wz[z]; p.bias = p.biasz[z]; p.C = p.Cz[z];
    p.Hf = p.Hfz[z]; p.Hb = p.Hbz[z]; p.rev = p.revz[z];
  }
  __shared__ float As[16][136];
  __shared__ float Bs[16][136];
  const int t  = threadIdx.x;
  const int tx = t & 15, ty = t >> 4;
  const int m0 = blockIdx.y * 128, n0 = blockIdx.x * 128;

  float acc[8][8];
#pragma unroll
  for (int i = 0; i < 8; ++i)
#pragma unroll
    for (int j = 0; j < 8; ++j) acc[i][j] = 0.f;

  const int KT  = (p.K + 15) >> 4;
  const int kk  = t & 15;
  const int sub = t >> 4;

  for (int kt = 0; kt < KT; ++kt) {
    const int k   = (kt << 4) + kk;
    const bool kok = (k < p.K);
#pragma unroll
    for (int l = 0; l < 8; ++l) {
      int mm = sub * 8 + l;
      int m = m0 + mm;
      As[kk][mm] = (kok && m < p.M) ? aacc(p, m, k) : 0.f;
      int n = n0 + mm;
      Bs[kk][mm] = (kok && n < p.N) ? p.W[(size_t)n * p.K + k] : 0.f;
    }
    __syncthreads();
#pragma unroll
    for (int q = 0; q < 16; ++q) {
      const float4 a0 = *(const float4*)&As[q][ty * 4];
      const float4 a1 = *(const float4*)&As[q][64 + ty * 4];
      const float4 b0 = *(const float4*)&Bs[q][tx * 4];
      const float4 b1 = *(const float4*)&Bs[q][64 + tx * 4];
      const float av[8] = {a0.x, a0.y, a0.z, a0.w, a1.x, a1.y, a1.z, a1.w};
      const float bv[8] = {b0.x, b0.y, b0.z, b0.w, b1.x, b1.y, b1.z, b1.w};
#pragma unroll
      for (int i = 0; i < 8; ++i)
#pragma unroll
        for (int j = 0; j < 8; ++j) acc[i][j] += av[i] * bv[j];
    }
    __syncthreads();
  }

#pragma unroll
  for (int i = 0; i < 8; ++i) {
    int m = m0 + (i < 4 ? ty * 4 + i : 64 + ty * 4 + (i - 4));
    if (m >= p.M) continue;
#pragma unroll
    for (int j = 0; j < 8; ++j) {
      int n = n0 + (j < 4 ? tx * 4 + j : 64 + tx * 4 + (j - 4));
      if (n >= p.N) continue;
      float v = acc[i][j] + p.bias[n];
      if (p.epi == 1)      v = (v > 0.f ? v : expm1f(v)) + aacc(p, m, n);
      else if (p.epi == 2) v = (v > 0.f ? v : expm1f(v));
      else if (p.epi == 3) v = v * p.MUL[(size_t)m * p.N + n];
      p.C[(size_t)m * p.N + n] = v;
    }
  }
}

// ---------------------------------------------------------------------------
// Persistent recurrent LSTM layer: 4 streams (lstm x dir), NBLK blocks each,
// 512 threads/block. Block b owns h indices [16b,16b+16) -> 64 gate rows;
// wave og (0..7) owns gate rows og*8..og*8+7; lane p (0..63) holds 8 weights
// per row at stride 64 (named f32x8 -> register/AGPR resident; confirmed
// round 6: no memory re-stream of weights).
// DATA-AS-SIGNAL sync: Hout pre-memset to 0xFF (NaN sentinel) by the host
// launch; producers store h via relaxed agent-scope atomics; every thread
// poll-loads ITS OWN h element until bits != sentinel. No counter, no
// vmcnt drain, no fences -- the data arrival is the barrier.
// ---------------------------------------------------------------------------
__global__ __launch_bounds__(512, 2) void lstm_layer_k(
    const float* __restrict__ Whh_u, const float* __restrict__ Whh_p,
    const float* __restrict__ XP,    // [4][S_SEQ][2048]
    float* __restrict__ Hout,        // [4][S_SEQ][512], pre-set to 0xFF
    int layer) {
  const int bid = blockIdx.x;
  const int s = bid & 3;        // stream: (lstm<<1)|dir
  const int b = bid >> 2;       // 0..NBLK-1
  const int t = threadIdx.x;    // 0..511
  const int p = t & 63;         // lane
  const int og = t >> 6;        // wave 0..7

  const float* W2 = ((s >> 1) ? Whh_p : Whh_u) +
                    (size_t)(layer * 2 + (s & 1)) * 2048 * 512;
  const float* xp = XP + (size_t)s * S_SEQ * 2048;
  float* hout = Hout + (size_t)s * S_SEQ * 512;

  __shared__ float h_lds[512];
  __shared__ float xp_lds[64];
  __shared__ float gates[64];

  // Register-resident weights: 8 named f32x8, statically indexed everywhere.
  f32x8 w0, w1, w2, w3, w4, w5, w6, w7;
#define LOADW(i)                                                         \
  {                                                                      \
    const int fr = og * 8 + i;                                           \
    const int row = ((fr >> 4) << 9) + (b << 4) + (fr & 15);             \
    const float* wr = W2 + (size_t)row * 512 + p;                        \
    w##i = (f32x8){wr[0],   wr[64],  wr[128], wr[192],                   \
                   wr[256], wr[320], wr[384], wr[448]};                  \
  }
  LOADW(0) LOADW(1) LOADW(2) LOADW(3) LOADW(4) LOADW(5) LOADW(6) LOADW(7)
#undef LOADW

  const int row64 = ((t >> 4) << 9) + (b << 4) + (t & 15);  // for t<64
  float xr = (t < 64) ? xp[row64] : 0.f;

  h_lds[t] = 0.f;
  float creg = 0.f;
  __syncthreads();

  for (int step = 0; step < S_SEQ; ++step) {
    if (t < 64) xp_lds[t] = xr;   // xp for current step
    __syncthreads();              // xp_lds + h_lds ready

    // prefetch next step's xp into register (hidden under the dot product)
    if (t < 64 && step + 1 < S_SEQ)
      xr = xp[(size_t)(step + 1) * 2048 + row64];

    float a0 = 0.f, a1 = 0.f, a2 = 0.f, a3 = 0.f;
    float a4 = 0.f, a5 = 0.f, a6 = 0.f, a7 = 0.f;
#pragma unroll
    for (int e = 0; e < 8; ++e) {
      const float hv = h_lds[p + (e << 6)];
      a0 += w0[e] * hv; a1 += w1[e] * hv; a2 += w2[e] * hv; a3 += w3[e] * hv;
      a4 += w4[e] * hv; a5 += w5[e] * hv; a6 += w6[e] * hv; a7 += w7[e] * hv;
    }
#pragma unroll
    for (int d = 32; d >= 1; d >>= 1) {
      a0 += __shfl_xor(a0, d, 64); a1 += __shfl_xor(a1, d, 64);
      a2 += __shfl_xor(a2, d, 64); a3 += __shfl_xor(a3, d, 64);
      a4 += __shfl_xor(a4, d, 64); a5 += __shfl_xor(a5, d, 64);
      a6 += __shfl_xor(a6, d, 64); a7 += __shfl_xor(a7, d, 64);
    }
    if (p == 0) {
      const int fb = og * 8;
      gates[fb + 0] = a0 + xp_lds[fb + 0];
      gates[fb + 1] = a1 + xp_lds[fb + 1];
      gates[fb + 2] = a2 + xp_lds[fb + 2];
      gates[fb + 3] = a3 + xp_lds[fb + 3];
      gates[fb + 4] = a4 + xp_lds[fb + 4];
      gates[fb + 5] = a5 + xp_lds[fb + 5];
      gates[fb + 6] = a6 + xp_lds[fb + 6];
      gates[fb + 7] = a7 + xp_lds[fb + 7];
    }
    __syncthreads();

    if (t < 16) {
      const float gi = gates[t], gf = gates[16 + t];
      const float gg = gates[32 + t], go = gates[48 + t];
      const float si = 1.f / (1.f + __expf(-gi));
      const float sf = 1.f / (1.f + __expf(-gf));
      const float so = 1.f / (1.f + __expf(-go));
      creg = sf * creg + si * tanhf(gg);
      const float h = so * tanhf(creg);
      __hip_atomic_store(&hout[(size_t)step * 512 + (b << 4) + t], h,
                         __ATOMIC_RELAXED, __HIP_MEMORY_SCOPE_AGENT);
    }
    // Data-as-signal: poll own element of this step's h until it is no
    // longer the 0xFF sentinel. Arrival of the bits IS the cross-block
    // barrier; loop-top __syncthreads orders h_lds write vs next reads.
    {
      union { float f; unsigned u; } v;
      do {
        v.f = __hip_atomic_load(&hout[(size_t)step * 512 + t],
                                __ATOMIC_RELAXED, __HIP_MEMORY_SCOPE_AGENT);
      } while (v.u == SENT_U);
      h_lds[t] = v.f;
    }
  }
}

// ---------------------------------------------------------------------------
// CRF: sequential scans (wave0 unary, wave1 pairwise) + score gathers
// (waves 2/3), then combine. Single block; in-wave lockstep avoids barriers.
// ---------------------------------------------------------------------------
__global__ __launch_bounds__(256) void crf_k(const float* __restrict__ FU,
                                             const float* __restrict__ FPp,
                                             const float* __restrict__ trans,
                                             const int* __restrict__ tags,
                                             float* __restrict__ out) {
  __shared__ float tr[144];
  __shared__ float fvU[NTAG];
  __shared__ float fvP[NTAG];
  __shared__ float pf[160];
  __shared__ float sc[2];
  const int t = threadIdx.x;
  if (t < 144) tr[t] = trans[t];
  if (t < NTAG) {
    fvU[t] = (t == START_TAG) ? 0.f : -100.f;
    fvP[t] = 0.f;
  }
  __syncthreads();
  const int w = t >> 6, l = t & 63;

  if (w == 0) {  // unary forward scan
    float featc = (l < NTAG) ? FU[l] : 0.f;
    for (int step = 0; step < T_SEQ; ++step) {
      float featn = 0.f;
      if (l < NTAG && step + 1 < T_SEQ) featn = FU[(size_t)(step + 1) * NTAG + l];
      if (l < NTAG) {
        float m = -1e30f;
#pragma unroll
        for (int i = 0; i < NTAG; ++i) m = fmaxf(m, fvU[i] + tr[i * NTAG + l]);
        float ss = 0.f;
#pragma unroll
        for (int i = 0; i < NTAG; ++i)
          ss += __expf(fvU[i] + tr[i * NTAG + l] - m);
        fvU[l] = m + __logf(ss) + featc;
      }
      featc = featn;
    }
  } else if (w == 1) {  // pairwise forward scan
    for (int q = l; q < 144; q += 64) pf[q] = FPp[q];
    for (int step = 0; step < T_SEQ + 1; ++step) {
      float nx0 = 0.f, nx1 = 0.f, nx2 = 0.f;
      if (step + 1 < T_SEQ + 1) {
        const float* src = FPp + (size_t)(step + 1) * 144;
        nx0 = src[l];
        nx1 = src[l + 64];
        if (l < 16) nx2 = src[l + 128];
      }
      float nf = 0.f;
      if (l < NTAG) {
        float m = -1e30f;
#pragma unroll
        for (int i = 0; i < NTAG; ++i) m = fmaxf(m, fvP[i] + pf[i * NTAG + l]);
        float ss = 0.f;
#pragma unroll
        for (int i = 0; i < NTAG; ++i)
          ss += __expf(fvP[i] + pf[i * NTAG + l] - m);
        nf = m + __logf(ss);
      }
      pf[l] = nx0;
      pf[l + 64] = nx1;
      if (l < 16) pf[l + 128] = nx2;
      if (l < NTAG) fvP[l] = nf;
    }
  } else if (w == 2) {  // score_u
    float acc = 0.f;
    for (int i = l; i < T_SEQ; i += 64) {
      const int tg = tags[i];
      const int pv = (i == 0) ? START_TAG : tags[i - 1];
      acc += FU[(size_t)i * NTAG + tg] + tr[pv * NTAG + tg];
    }
    if (l == 0) acc += tr[tags[T_SEQ - 1] * NTAG + STOP_TAG];
#pragma unroll
    for (int d = 32; d >= 1; d >>= 1) acc += __shfl_xor(acc, d, 64);
    if (l == 0) sc[0] = acc;
  } else {  // score_p
    float acc = 0.f;
    for (int i = l; i < T_SEQ + 1; i += 64) {
      const int a = (i == 0) ? START_TAG : tags[i - 1];
      const int b2 = (i < T_SEQ) ? tags[i] : STOP_TAG;
      acc += FPp[(size_t)i * 144 + a * NTAG + b2];
    }
#pragma unroll
    for (int d = 32; d >= 1; d >>= 1) acc += __shfl_xor(acc, d, 64);
    if (l == 0) sc[1] = acc;
  }
  __syncthreads();
  if (t == 0) {
    float m = -1e30f;
    for (int i = 0; i < NTAG; ++i)
      m = fmaxf(m, fvU[i] + tr[i * NTAG + STOP_TAG]);
    float ss = 0.f;
    for (int i = 0; i < NTAG; ++i)
      ss += __expf(fvU[i] + tr[i * NTAG + STOP_TAG] - m);
    const float alpha_u = m + __logf(ss);
    float m2 = -1e30f;
    for (int i = 0; i < NTAG; ++i) m2 = fmaxf(m2, fvP[i]);
    float s2 = 0.f;
    for (int i = 0; i < NTAG; ++i) s2 += __expf(fvP[i] - m2);
    const float alpha_p = m2 + __logf(s2);
    out[0] = alpha_u - sc[0] + alpha_p - sc[1];
  }
}

// ---------------------------------------------------------------------------
// Workspace layout (float offsets)
// ---------------------------------------------------------------------------
static const size_t F_XP  = 0;                         // 4*2050*2048
static const size_t F_H0  = 16793600;                  // 4*2050*512
static const size_t F_H1  = 20992000;                  // 4*2050*512
static const size_t F_FC  = 25190400;                  // 2048*1024
static const size_t F_FU  = 27287552;                  // 2048*12
static const size_t F_UB  = 27312128;                  // 2049*512
static const size_t F_HP  = 28361216;                  // 2049*512
static const size_t F_FI  = 29410304;                  // 2049*300
static const size_t F_FO  = 30025004;                  // 2049*300
static const size_t F_FP  = 30639704;                  // 2049*144

extern "C" void kernel_launch(void* const* d_in, const int* in_sizes, int n_in,
                              void* d_out, int out_size, void* d_ws,
                              size_t ws_size, hipStream_t stream) {
  (void)in_sizes; (void)n_in; (void)out_size; (void)ws_size;
  const float* embeds = (const float*)d_in[0];
  const int*   tags   = (const int*)d_in[1];
  const float* uWih   = (const float*)d_in[2];
  const float* uWhh   = (const float*)d_in[3];
  const float* ub     = (const float*)d_in[4];
  const float* pWih   = (const float*)d_in[5];
  const float* pWhh   = (const float*)d_in[6];
  const float* pb     = (const float*)d_in[7];
  const float* ufcW   = (const float*)d_in[8];
  const float* ufcb   = (const float*)d_in[9];
  const float* h2tW   = (const float*)d_in[10];
  const float* h2tb   = (const float*)d_in[11];
  const float* trans  = (const float*)d_in[12];
  const float* UW     = (const float*)d_in[13];
  const float* Ub     = (const float*)d_in[14];
  const float* VW     = (const float*)d_in[15];
  const float* Vb     = (const float*)d_in[16];
  const float* PW     = (const float*)d_in[17];
  const float* Pb     = (const float*)d_in[18];
  const float* pwW    = (const float*)d_in[19];
  const float* pwb    = (const float*)d_in[20];
  const float* ppW    = (const float*)d_in[21];
  const float* ppb    = (const float*)d_in[22];
  float* out = (float*)d_out;
  float* F = (float*)d_ws;

  // Sentinel-fill the h broadcast buffers (data-as-signal sync).
  (void)hipMemsetAsync(F + F_H0, 0xFF, (size_t)4 * S_SEQ * 512 * sizeof(float),
                       stream);
  (void)hipMemsetAsync(F + F_H1, 0xFF, (size_t)4 * S_SEQ * 512 * sizeof(float),
                       stream);

  auto launch = [&](const GemmP& p) {
    dim3 g((p.N + 127) / 128, (p.M + 127) / 128);
    gemm_k<<<g, 256, 0, stream>>>(p);
  };
  auto launch4 = [&](const GemmP& p) {
    dim3 g((p.N + 127) / 128, (p.M + 127) / 128, 4);
    gemm_k<<<g, 256, 0, stream>>>(p);
  };

  // ---- layer-0 xp (4 streams, one dispatch) ----
  {
    GemmP p{};
    p.M = S_SEQ; p.N = 2048; p.K = 1024;
    p.amode = 0; p.A = embeds; p.lda = 1024; p.rowoff = 0;
    p.epi = 0;
    for (int s = 0; s < 4; ++s) {
      const int lstm = s >> 1, d = s & 1;
      p.Wz[s]    = (lstm ? pWih : uWih) + (size_t)d * 2048 * 1024;
      p.biasz[s] = (lstm ? pb : ub) + (size_t)d * 2048;
      p.Cz[s]    = F + F_XP + (size_t)s * S_SEQ * 2048;
      p.revz[s]  = d;
      p.Hfz[s] = nullptr; p.Hbz[s] = nullptr;
    }
    p.W = p.Wz[0]; p.bias = p.biasz[0]; p.C = p.Cz[0]; p.rev = 0;
    launch4(p);
  }
  lstm_layer_k<<<4 * NBLK, 512, 0, stream>>>(uWhh, pWhh, F + F_XP, F + F_H0, 0);
  // ---- layer-1 xp (4 streams, one dispatch) ----
  {
    GemmP p{};
    p.M = S_SEQ; p.N = 2048; p.K = 1024;
    p.amode = 1; p.rowoff = 0;
    p.epi = 0;
    for (int s = 0; s < 4; ++s) {
      const int lstm = s >> 1, d = s & 1;
      p.Wz[s]    = (lstm ? pWih : uWih) + (size_t)(2 + d) * 2048 * 1024;
      p.biasz[s] = (lstm ? pb : ub) + (size_t)(2 + d) * 2048;
      p.Cz[s]    = F + F_XP + (size_t)s * S_SEQ * 2048;
      p.revz[s]  = d;
      p.Hfz[s]   = F + F_H0 + (size_t)(lstm * 2 + 0) * S_SEQ * 512;
      p.Hbz[s]   = F + F_H0 + (size_t)(lstm * 2 + 1) * S_SEQ * 512;
    }
    p.W = p.Wz[0]; p.bias = p.biasz[0]; p.C = p.Cz[0]; p.rev = 0;
    p.Hf = p.Hfz[0]; p.Hb = p.Hbz[0];
    launch4(p);
  }
  lstm_layer_k<<<4 * NBLK, 512, 0, stream>>>(uWhh, pWhh, F + F_XP, F + F_H1, 1);
  // ---- unary head ----
  {
    GemmP p{};
    p.W = ufcW; p.bias = ufcb; p.C = F + F_FC;
    p.M = 2048; p.N = 1024; p.K = 1024;
    p.amode = 1; p.rev = 0; p.rowoff = 1;
    p.Hf = F + F_H1; p.Hb = F + F_H1 + (size_t)1 * S_SEQ * 512;
    p.epi = 1;
    launch(p);
  }
  {
    GemmP p{};
    p.W = h2tW; p.bias = h2tb; p.C = F + F_FU;
    p.M = 2048; p.N = 12; p.K = 1024;
    p.amode = 0; p.A = F + F_FC; p.lda = 1024; p.rev = 0; p.rowoff = 0;
    p.epi = 0;
    launch(p);
  }
  // ---- pairwise head ----
  {
    GemmP p{};
    p.W = UW; p.bias = Ub; p.C = F + F_UB;
    p.M = 2049; p.N = 512; p.K = 1024;
    p.amode = 1; p.rev = 0; p.rowoff = 0;
    p.Hf = F + F_H1 + (size_t)2 * S_SEQ * 512;
    p.Hb = F + F_H1 + (size_t)3 * S_SEQ * 512;
    p.epi = 0;
    launch(p);
  }
  {
    GemmP p{};
    p.W = VW; p.bias = Vb; p.C = F + F_HP;
    p.M = 2049; p.N = 512; p.K = 1024;
    p.amode = 1; p.rev = 0; p.rowoff = 1;
    p.Hf = F + F_H1 + (size_t)2 * S_SEQ * 512;
    p.Hb = F + F_H1 + (size_t)3 * S_SEQ * 512;
    p.epi = 3; p.MUL = F + F_UB;
    launch(p);
  }
  {
    GemmP p{};
    p.W = PW; p.bias = Pb; p.C = F + F_FI;
    p.M = 2049; p.N = 300; p.K = 512;
    p.amode = 0; p.A = F + F_HP; p.lda = 512; p.rev = 0; p.rowoff = 0;
    p.epi = 2;
    launch(p);
  }
  {
    GemmP p{};
    p.W = pwW; p.bias = pwb; p.C = F + F_FO;
    p.M = 2049; p.N = 300; p.K = 300;
    p.amode = 0; p.A = F + F_FI; p.lda = 300; p.rev = 0; p.rowoff = 0;
    p.epi = 1;
    launch(p);
  }
  {
    GemmP p{};
    p.W = ppW; p.bias = ppb; p.C = F + F_FP;
    p.M = 2049; p.N = 144; p.K = 300;
    p.amode = 0; p.A = F + F_FO; p.lda = 300; p.rev = 0; p.rowoff = 0;
    p.epi = 0;
    launch(p);
  }
  crf_k<<<1, 256, 0, stream>>>(F + F_FU, F + F_FP, trans, tags, out);
}

// Round 9
// 12611.143 us; speedup vs baseline: 1.3372x; 1.2522x over previous
//
#include <hip/hip_runtime.h>
#include <math.h>

#define T_SEQ 2048
#define S_SEQ 2050   // T + 2
#define NTAG 12
#define START_TAG 10
#define STOP_TAG 11
#define NBLK 32      // blocks per LSTM stream
#define SENT_U 0xFFFFFFFFu   // memset(0xFF) sentinel: NaN bit pattern, h in (-1,1) never produces it

typedef float f32x8 __attribute__((ext_vector_type(8)));
typedef float f32x4 __attribute__((ext_vector_type(4)));
typedef short bf16x8 __attribute__((ext_vector_type(8)));

// ---------------------------------------------------------------------------
// GemmP: C[M,N] = Aacc[M,K] @ W[N,K]^T + bias, fused epilogues.
// amode 0: A[r][k] direct (row r possibly reversed). amode 1: concat of two
// h-buffers: lo[r] = concat(Hf[r], Hb[S-1-r]).
// epi 0: +bias; 1: elu(+bias)+Aacc(m,n) residual; 2: elu(+bias); 3: (+bias)*MUL
// gridDim.z > 1: per-z pointer arrays override W/bias/C/Hf/Hb/rev.
// ---------------------------------------------------------------------------
struct GemmP {
  const float* W; const float* bias; float* C;
  int M, N, K;
  int amode; const float* A; int lda; int rev; int rowoff;
  const float* Hf; const float* Hb;
  int epi; const float* MUL;
  const float* Wz[4]; const float* biasz[4]; float* Cz[4];
  const float* Hfz[4]; const float* Hbz[4]; int revz[4];
};

__device__ __forceinline__ float aacc(const GemmP& p, int m, int k) {
  int r = p.rowoff + m;
  if (p.rev) r = (S_SEQ - 1) - r;
  if (p.amode == 0) return p.A[(size_t)r * p.lda + k];
  return (k < 512) ? p.Hf[(size_t)r * 512 + k]
                   : p.Hb[(size_t)(S_SEQ - 1 - r) * 512 + (k - 512)];
}

// Pointer to 16 consecutive k-elements at row m (k is 16-aligned; for
// amode 1 a 16-aligned chunk never straddles the 512 boundary).
__device__ __forceinline__ const float* arowp(const GemmP& p, int m, int k) {
  int r = p.rowoff + m;
  if (p.rev) r = (S_SEQ - 1) - r;
  if (p.amode == 0) return p.A + (size_t)r * p.lda + k;
  return (k < 512) ? p.Hf + (size_t)r * 512 + k
                   : p.Hb + (size_t)(S_SEQ - 1 - r) * 512 + (k - 512);
}

__device__ __forceinline__ unsigned short f2bf(float f) {  // RNE f32->bf16
  union { float f; unsigned u; } x; x.f = f;
  unsigned r = x.u + 0x7FFFu + ((x.u >> 16) & 1u);
  return (unsigned short)(r >> 16);
}
__device__ __forceinline__ unsigned bfpack(float a, float b) {
  return (unsigned)f2bf(a) | ((unsigned)f2bf(b) << 16);
}

// ---------------------------------------------------------------------------
// bf16 MFMA GEMM (fp32 accumulate, fp32 bias/epilogue).
// 128x128 tile, BK=32, 256 threads = 4 waves in 2x2; each wave owns a 64x64
// sub-tile = 4x4 frags of 16x16, one mfma_f32_16x16x32_bf16 per frag per
// k-tile. Frag layout (guide Sec.3 / m89): A lane l elem j = A[l&15][(l>>4)*8+j];
// B lane l elem j = B^T[l&15][(l>>4)*8+j] (our W rows ARE B^T rows);
// C/D: col=lane&15, row=(lane>>4)*4+reg.
// ---------------------------------------------------------------------------
__global__ __launch_bounds__(256) void gemm_mfma_k(GemmP p) {
  if (gridDim.z > 1) {
    const int z = blockIdx.z;
    p.W = p.Wz[z]; p.bias = p.biasz[z]; p.C = p.Cz[z];
    p.Hf = p.Hfz[z]; p.Hb = p.Hbz[z]; p.rev = p.revz[z];
  }
  __shared__ unsigned short Abf[128][32];
  __shared__ unsigned short Bbf[128][32];   // [n-local][k-local]
  const int t  = threadIdx.x;
  const int m0 = blockIdx.y * 128, n0 = blockIdx.x * 128;
  const int l  = t & 63, wv = t >> 6;
  const int wr = wv >> 1, wc = wv & 1;     // wave 2x2 grid
  const int fr = l & 15, fc = l >> 4;      // frag row / k-chunk (0..3)
  const int sr = t >> 1, sc = (t & 1) << 4;  // staging: row, col-base (16-wide)

  f32x4 acc[4][4];
#pragma unroll
  for (int mi = 0; mi < 4; ++mi)
#pragma unroll
    for (int ni = 0; ni < 4; ++ni) acc[mi][ni] = (f32x4){0.f, 0.f, 0.f, 0.f};

  const int KT = (p.K + 31) >> 5;
  for (int kt = 0; kt < KT; ++kt) {
    const int k = (kt << 5) + sc;
    // ---- stage A chunk (16 fp32 -> 16 bf16) ----
    {
      unsigned short* dst = &Abf[sr][sc];
      const int m = m0 + sr;
      if (m < p.M && k < p.K) {
        const float* src = arowp(p, m, k);
        if (k + 16 <= p.K) {
#pragma unroll
          for (int q = 0; q < 4; ++q) {
            const float4 v = ((const float4*)src)[q];
            ((uint2*)dst)[q] = make_uint2(bfpack(v.x, v.y), bfpack(v.z, v.w));
          }
        } else {
          for (int j = 0; j < 16; ++j)
            dst[j] = (k + j < p.K) ? f2bf(src[j]) : 0;
        }
      } else {
        ((uint4*)dst)[0] = make_uint4(0, 0, 0, 0);
        ((uint4*)dst)[1] = make_uint4(0, 0, 0, 0);
      }
    }
    // ---- stage B chunk (W row n) ----
    {
      unsigned short* dst = &Bbf[sr][sc];
      const int n = n0 + sr;
      if (n < p.N && k < p.K) {
        const float* src = p.W + (size_t)n * p.K + k;
        if (k + 16 <= p.K) {
#pragma unroll
          for (int q = 0; q < 4; ++q) {
            const float4 v = ((const float4*)src)[q];
            ((uint2*)dst)[q] = make_uint2(bfpack(v.x, v.y), bfpack(v.z, v.w));
          }
        } else {
          for (int j = 0; j < 16; ++j)
            dst[j] = (k + j < p.K) ? f2bf(src[j]) : 0;
        }
      } else {
        ((uint4*)dst)[0] = make_uint4(0, 0, 0, 0);
        ((uint4*)dst)[1] = make_uint4(0, 0, 0, 0);
      }
    }
    __syncthreads();
    // ---- fragments + 16 MFMAs ----
    bf16x8 af[4], bfr[4];
#pragma unroll
    for (int mi = 0; mi < 4; ++mi)
      af[mi] = *(const bf16x8*)&Abf[(wr << 6) + (mi << 4) + fr][fc << 3];
#pragma unroll
    for (int ni = 0; ni < 4; ++ni)
      bfr[ni] = *(const bf16x8*)&Bbf[(wc << 6) + (ni << 4) + fr][fc << 3];
#pragma unroll
    for (int mi = 0; mi < 4; ++mi)
#pragma unroll
      for (int ni = 0; ni < 4; ++ni)
        acc[mi][ni] = __builtin_amdgcn_mfma_f32_16x16x32_bf16(
            af[mi], bfr[ni], acc[mi][ni], 0, 0, 0);
    __syncthreads();
  }
  // ---- epilogue (fp32) ----
#pragma unroll
  for (int mi = 0; mi < 4; ++mi) {
#pragma unroll
    for (int ni = 0; ni < 4; ++ni) {
#pragma unroll
      for (int i = 0; i < 4; ++i) {
        const int m = m0 + (wr << 6) + (mi << 4) + (fc << 2) + i;
        const int n = n0 + (wc << 6) + (ni << 4) + fr;
        if (m < p.M && n < p.N) {
          float v = acc[mi][ni][i] + p.bias[n];
          if (p.epi == 1)      v = (v > 0.f ? v : expm1f(v)) + aacc(p, m, n);
          else if (p.epi == 2) v = (v > 0.f ? v : expm1f(v));
          else if (p.epi == 3) v = v * p.MUL[(size_t)m * p.N + n];
          p.C[(size_t)m * p.N + n] = v;
        }
      }
    }
  }
}

// ---------------------------------------------------------------------------
// Persistent recurrent LSTM layer (UNCHANGED from round 8): 4 streams, NBLK
// blocks each, 512 threads. Weights register/AGPR-resident (named f32x8).
// Data-as-signal sync: Hout pre-memset to 0xFF; producers store h (relaxed,
// agent scope); every thread polls its own h word until != sentinel.
// ---------------------------------------------------------------------------
__global__ __launch_bounds__(512, 2) void lstm_layer_k(
    const float* __restrict__ Whh_u, const float* __restrict__ Whh_p,
    const float* __restrict__ XP,    // [4][S_SEQ][2048]
    float* __restrict__ Hout,        // [4][S_SEQ][512], pre-set to 0xFF
    int layer) {
  const int bid = blockIdx.x;
  const int s = bid & 3;        // stream: (lstm<<1)|dir
  const int b = bid >> 2;       // 0..NBLK-1
  const int t = threadIdx.x;    // 0..511
  const int p = t & 63;         // lane
  const int og = t >> 6;        // wave 0..7

  const float* W2 = ((s >> 1) ? Whh_p : Whh_u) +
                    (size_t)(layer * 2 + (s & 1)) * 2048 * 512;
  const float* xp = XP + (size_t)s * S_SEQ * 2048;
  float* hout = Hout + (size_t)s * S_SEQ * 512;

  __shared__ float h_lds[512];
  __shared__ float xp_lds[64];
  __shared__ float gates[64];

  f32x8 w0, w1, w2, w3, w4, w5, w6, w7;
#define LOADW(i)                                                         \
  {                                                                      \
    const int fr_ = og * 8 + i;                                          \
    const int row = ((fr_ >> 4) << 9) + (b << 4) + (fr_ & 15);           \
    const float* wr_ = W2 + (size_t)row * 512 + p;                       \
    w##i = (f32x8){wr_[0],   wr_[64],  wr_[128], wr_[192],               \
                   wr_[256], wr_[320], wr_[384], wr_[448]};              \
  }
  LOADW(0) LOADW(1) LOADW(2) LOADW(3) LOADW(4) LOADW(5) LOADW(6) LOADW(7)
#undef LOADW

  const int row64 = ((t >> 4) << 9) + (b << 4) + (t & 15);  // for t<64
  float xr = (t < 64) ? xp[row64] : 0.f;

  h_lds[t] = 0.f;
  float creg = 0.f;
  __syncthreads();

  for (int step = 0; step < S_SEQ; ++step) {
    if (t < 64) xp_lds[t] = xr;   // xp for current step
    __syncthreads();              // xp_lds + h_lds ready

    if (t < 64 && step + 1 < S_SEQ)
      xr = xp[(size_t)(step + 1) * 2048 + row64];

    float a0 = 0.f, a1 = 0.f, a2 = 0.f, a3 = 0.f;
    float a4 = 0.f, a5 = 0.f, a6 = 0.f, a7 = 0.f;
#pragma unroll
    for (int e = 0; e < 8; ++e) {
      const float hv = h_lds[p + (e << 6)];
      a0 += w0[e] * hv; a1 += w1[e] * hv; a2 += w2[e] * hv; a3 += w3[e] * hv;
      a4 += w4[e] * hv; a5 += w5[e] * hv; a6 += w6[e] * hv; a7 += w7[e] * hv;
    }
#pragma unroll
    for (int d = 32; d >= 1; d >>= 1) {
      a0 += __shfl_xor(a0, d, 64); a1 += __shfl_xor(a1, d, 64);
      a2 += __shfl_xor(a2, d, 64); a3 += __shfl_xor(a3, d, 64);
      a4 += __shfl_xor(a4, d, 64); a5 += __shfl_xor(a5, d, 64);
      a6 += __shfl_xor(a6, d, 64); a7 += __shfl_xor(a7, d, 64);
    }
    if (p == 0) {
      const int fb = og * 8;
      gates[fb + 0] = a0 + xp_lds[fb + 0];
      gates[fb + 1] = a1 + xp_lds[fb + 1];
      gates[fb + 2] = a2 + xp_lds[fb + 2];
      gates[fb + 3] = a3 + xp_lds[fb + 3];
      gates[fb + 4] = a4 + xp_lds[fb + 4];
      gates[fb + 5] = a5 + xp_lds[fb + 5];
      gates[fb + 6] = a6 + xp_lds[fb + 6];
      gates[fb + 7] = a7 + xp_lds[fb + 7];
    }
    __syncthreads();

    if (t < 16) {
      const float gi = gates[t], gf = gates[16 + t];
      const float gg = gates[32 + t], go = gates[48 + t];
      const float si = 1.f / (1.f + __expf(-gi));
      const float sf = 1.f / (1.f + __expf(-gf));
      const float so = 1.f / (1.f + __expf(-go));
      creg = sf * creg + si * tanhf(gg);
      const float h = so * tanhf(creg);
      __hip_atomic_store(&hout[(size_t)step * 512 + (b << 4) + t], h,
                         __ATOMIC_RELAXED, __HIP_MEMORY_SCOPE_AGENT);
    }
    {
      union { float f; unsigned u; } v;
      do {
        v.f = __hip_atomic_load(&hout[(size_t)step * 512 + t],
                                __ATOMIC_RELAXED, __HIP_MEMORY_SCOPE_AGENT);
      } while (v.u == SENT_U);
      h_lds[t] = v.f;
    }
  }
}

// ---------------------------------------------------------------------------
// CRF (unchanged).
// ---------------------------------------------------------------------------
__global__ __launch_bounds__(256) void crf_k(const float* __restrict__ FU,
                                             const float* __restrict__ FPp,
                                             const float* __restrict__ trans,
                                             const int* __restrict__ tags,
                                             float* __restrict__ out) {
  __shared__ float tr[144];
  __shared__ float fvU[NTAG];
  __shared__ float fvP[NTAG];
  __shared__ float pf[160];
  __shared__ float sc[2];
  const int t = threadIdx.x;
  if (t < 144) tr[t] = trans[t];
  if (t < NTAG) {
    fvU[t] = (t == START_TAG) ? 0.f : -100.f;
    fvP[t] = 0.f;
  }
  __syncthreads();
  const int w = t >> 6, l = t & 63;

  if (w == 0) {
    float featc = (l < NTAG) ? FU[l] : 0.f;
    for (int step = 0; step < T_SEQ; ++step) {
      float featn = 0.f;
      if (l < NTAG && step + 1 < T_SEQ) featn = FU[(size_t)(step + 1) * NTAG + l];
      if (l < NTAG) {
        float m = -1e30f;
#pragma unroll
        for (int i = 0; i < NTAG; ++i) m = fmaxf(m, fvU[i] + tr[i * NTAG + l]);
        float ss = 0.f;
#pragma unroll
        for (int i = 0; i < NTAG; ++i)
          ss += __expf(fvU[i] + tr[i * NTAG + l] - m);
        fvU[l] = m + __logf(ss) + featc;
      }
      featc = featn;
    }
  } else if (w == 1) {
    for (int q = l; q < 144; q += 64) pf[q] = FPp[q];
    for (int step = 0; step < T_SEQ + 1; ++step) {
      float nx0 = 0.f, nx1 = 0.f, nx2 = 0.f;
      if (step + 1 < T_SEQ + 1) {
        const float* src = FPp + (size_t)(step + 1) * 144;
        nx0 = src[l];
        nx1 = src[l + 64];
        if (l < 16) nx2 = src[l + 128];
      }
      float nf = 0.f;
      if (l < NTAG) {
        float m = -1e30f;
#pragma unroll
        for (int i = 0; i < NTAG; ++i) m = fmaxf(m, fvP[i] + pf[i * NTAG + l]);
        float ss = 0.f;
#pragma unroll
        for (int i = 0; i < NTAG; ++i)
          ss += __expf(fvP[i] + pf[i * NTAG + l] - m);
        nf = m + __logf(ss);
      }
      pf[l] = nx0;
      pf[l + 64] = nx1;
      if (l < 16) pf[l + 128] = nx2;
      if (l < NTAG) fvP[l] = nf;
    }
  } else if (w == 2) {
    float acc = 0.f;
    for (int i = l; i < T_SEQ; i += 64) {
      const int tg = tags[i];
      const int pv = (i == 0) ? START_TAG : tags[i - 1];
      acc += FU[(size_t)i * NTAG + tg] + tr[pv * NTAG + tg];
    }
    if (l == 0) acc += tr[tags[T_SEQ - 1] * NTAG + STOP_TAG];
#pragma unroll
    for (int d = 32; d >= 1; d >>= 1) acc += __shfl_xor(acc, d, 64);
    if (l == 0) sc[0] = acc;
  } else {
    float acc = 0.f;
    for (int i = l; i < T_SEQ + 1; i += 64) {
      const int a = (i == 0) ? START_TAG : tags[i - 1];
      const int b2 = (i < T_SEQ) ? tags[i] : STOP_TAG;
      acc += FPp[(size_t)i * 144 + a * NTAG + b2];
    }
#pragma unroll
    for (int d = 32; d >= 1; d >>= 1) acc += __shfl_xor(acc, d, 64);
    if (l == 0) sc[1] = acc;
  }
  __syncthreads();
  if (t == 0) {
    float m = -1e30f;
    for (int i = 0; i < NTAG; ++i)
      m = fmaxf(m, fvU[i] + tr[i * NTAG + STOP_TAG]);
    float ss = 0.f;
    for (int i = 0; i < NTAG; ++i)
      ss += __expf(fvU[i] + tr[i * NTAG + STOP_TAG] - m);
    const float alpha_u = m + __logf(ss);
    float m2 = -1e30f;
    for (int i = 0; i < NTAG; ++i) m2 = fmaxf(m2, fvP[i]);
    float s2 = 0.f;
    for (int i = 0; i < NTAG; ++i) s2 += __expf(fvP[i] - m2);
    const float alpha_p = m2 + __logf(s2);
    out[0] = alpha_u - sc[0] + alpha_p - sc[1];
  }
}

// ---------------------------------------------------------------------------
// Workspace layout (float offsets)
// ---------------------------------------------------------------------------
static const size_t F_XP  = 0;                         // 4*2050*2048
static const size_t F_H0  = 16793600;                  // 4*2050*512
static const size_t F_H1  = 20992000;                  // 4*2050*512
static const size_t F_FC  = 25190400;                  // 2048*1024
static const size_t F_FU  = 27287552;                  // 2048*12
static const size_t F_UB  = 27312128;                  // 2049*512
static const size_t F_HP  = 28361216;                  // 2049*512
static const size_t F_FI  = 29410304;                  // 2049*300
static const size_t F_FO  = 30025004;                  // 2049*300
static const size_t F_FP  = 30639704;                  // 2049*144

extern "C" void kernel_launch(void* const* d_in, const int* in_sizes, int n_in,
                              void* d_out, int out_size, void* d_ws,
                              size_t ws_size, hipStream_t stream) {
  (void)in_sizes; (void)n_in; (void)out_size; (void)ws_size;
  const float* embeds = (const float*)d_in[0];
  const int*   tags   = (const int*)d_in[1];
  const float* uWih   = (const float*)d_in[2];
  const float* uWhh   = (const float*)d_in[3];
  const float* ub     = (const float*)d_in[4];
  const float* pWih   = (const float*)d_in[5];
  const float* pWhh   = (const float*)d_in[6];
  const float* pb     = (const float*)d_in[7];
  const float* ufcW   = (const float*)d_in[8];
  const float* ufcb   = (const float*)d_in[9];
  const float* h2tW   = (const float*)d_in[10];
  const float* h2tb   = (const float*)d_in[11];
  const float* trans  = (const float*)d_in[12];
  const float* UW     = (const float*)d_in[13];
  const float* Ub     = (const float*)d_in[14];
  const float* VW     = (const float*)d_in[15];
  const float* Vb     = (const float*)d_in[16];
  const float* PW     = (const float*)d_in[17];
  const float* Pb     = (const float*)d_in[18];
  const float* pwW    = (const float*)d_in[19];
  const float* pwb    = (const float*)d_in[20];
  const float* ppW    = (const float*)d_in[21];
  const float* ppb    = (const float*)d_in[22];
  float* out = (float*)d_out;
  float* F = (float*)d_ws;

  // Sentinel-fill the h broadcast buffers (data-as-signal sync).
  (void)hipMemsetAsync(F + F_H0, 0xFF, (size_t)4 * S_SEQ * 512 * sizeof(float),
                       stream);
  (void)hipMemsetAsync(F + F_H1, 0xFF, (size_t)4 * S_SEQ * 512 * sizeof(float),
                       stream);

  auto launch = [&](const GemmP& p) {
    dim3 g((p.N + 127) / 128, (p.M + 127) / 128);
    gemm_mfma_k<<<g, 256, 0, stream>>>(p);
  };
  auto launch4 = [&](const GemmP& p) {
    dim3 g((p.N + 127) / 128, (p.M + 127) / 128, 4);
    gemm_mfma_k<<<g, 256, 0, stream>>>(p);
  };

  // ---- layer-0 xp (4 streams, one dispatch) ----
  {
    GemmP p{};
    p.M = S_SEQ; p.N = 2048; p.K = 1024;
    p.amode = 0; p.A = embeds; p.lda = 1024; p.rowoff = 0;
    p.epi = 0;
    for (int s = 0; s < 4; ++s) {
      const int lstm = s >> 1, d = s & 1;
      p.Wz[s]    = (lstm ? pWih : uWih) + (size_t)d * 2048 * 1024;
      p.biasz[s] = (lstm ? pb : ub) + (size_t)d * 2048;
      p.Cz[s]    = F + F_XP + (size_t)s * S_SEQ * 2048;
      p.revz[s]  = d;
      p.Hfz[s] = nullptr; p.Hbz[s] = nullptr;
    }
    p.W = p.Wz[0]; p.bias = p.biasz[0]; p.C = p.Cz[0]; p.rev = 0;
    launch4(p);
  }
  lstm_layer_k<<<4 * NBLK, 512, 0, stream>>>(uWhh, pWhh, F + F_XP, F + F_H0, 0);
  // ---- layer-1 xp (4 streams, one dispatch) ----
  {
    GemmP p{};
    p.M = S_SEQ; p.N = 2048; p.K = 1024;
    p.amode = 1; p.rowoff = 0;
    p.epi = 0;
    for (int s = 0; s < 4; ++s) {
      const int lstm = s >> 1, d = s & 1;
      p.Wz[s]    = (lstm ? pWih : uWih) + (size_t)(2 + d) * 2048 * 1024;
      p.biasz[s] = (lstm ? pb : ub) + (size_t)(2 + d) * 2048;
      p.Cz[s]    = F + F_XP + (size_t)s * S_SEQ * 2048;
      p.revz[s]  = d;
      p.Hfz[s]   = F + F_H0 + (size_t)(lstm * 2 + 0) * S_SEQ * 512;
      p.Hbz[s]   = F + F_H0 + (size_t)(lstm * 2 + 1) * S_SEQ * 512;
    }
    p.W = p.Wz[0]; p.bias = p.biasz[0]; p.C = p.Cz[0]; p.rev = 0;
    p.Hf = p.Hfz[0]; p.Hb = p.Hbz[0];
    launch4(p);
  }
  lstm_layer_k<<<4 * NBLK, 512, 0, stream>>>(uWhh, pWhh, F + F_XP, F + F_H1, 1);
  // ---- unary head ----
  {
    GemmP p{};
    p.W = ufcW; p.bias = ufcb; p.C = F + F_FC;
    p.M = 2048; p.N = 1024; p.K = 1024;
    p.amode = 1; p.rev = 0; p.rowoff = 1;
    p.Hf = F + F_H1; p.Hb = F + F_H1 + (size_t)1 * S_SEQ * 512;
    p.epi = 1;
    launch(p);
  }
  {
    GemmP p{};
    p.W = h2tW; p.bias = h2tb; p.C = F + F_FU;
    p.M = 2048; p.N = 12; p.K = 1024;
    p.amode = 0; p.A = F + F_FC; p.lda = 1024; p.rev = 0; p.rowoff = 0;
    p.epi = 0;
    launch(p);
  }
  // ---- pairwise head ----
  {
    GemmP p{};
    p.W = UW; p.bias = Ub; p.C = F + F_UB;
    p.M = 2049; p.N = 512; p.K = 1024;
    p.amode = 1; p.rev = 0; p.rowoff = 0;
    p.Hf = F + F_H1 + (size_t)2 * S_SEQ * 512;
    p.Hb = F + F_H1 + (size_t)3 * S_SEQ * 512;
    p.epi = 0;
    launch(p);
  }
  {
    GemmP p{};
    p.W = VW; p.bias = Vb; p.C = F + F_HP;
    p.M = 2049; p.N = 512; p.K = 1024;
    p.amode = 1; p.rev = 0; p.rowoff = 1;
    p.Hf = F + F_H1 + (size_t)2 * S_SEQ * 512;
    p.Hb = F + F_H1 + (size_t)3 * S_SEQ * 512;
    p.epi = 3; p.MUL = F + F_UB;
    launch(p);
  }
  {
    GemmP p{};
    p.W = PW; p.bias = Pb; p.C = F + F_FI;
    p.M = 2049; p.N = 300; p.K = 512;
    p.amode = 0; p.A = F + F_HP; p.lda = 512; p.rev = 0; p.rowoff = 0;
    p.epi = 2;
    launch(p);
  }
  {
    GemmP p{};
    p.W = pwW; p.bias = pwb; p.C = F + F_FO;
    p.M = 2049; p.N = 300; p.K = 300;
    p.amode = 0; p.A = F + F_FI; p.lda = 300; p.rev = 0; p.rowoff = 0;
    p.epi = 1;
    launch(p);
  }
  {
    GemmP p{};
    p.W = ppW; p.bias = ppb; p.C = F + F_FP;
    p.M = 2049; p.N = 144; p.K = 300;
    p.amode = 0; p.A = F + F_FO; p.lda = 300; p.rev = 0; p.rowoff = 0;
    p.epi = 0;
    launch(p);
  }
  crf_k<<<1, 256, 0, stream>>>(F + F_FU, F + F_FP, trans, tags, out);
}